// Round 10
// baseline (113.668 us; speedup 1.0000x reference)
//
#include <hip/hip_runtime.h>

#define MK 4096

typedef int v4i __attribute__((ext_vector_type(4)));
typedef int v16i __attribute__((ext_vector_type(16)));

#define MFMA32(a, b, c) __builtin_amdgcn_mfma_i32_32x32x32_i8(a, b, c, 0, 0, 0)

#define GLOAD_LDS16(gp, lp) \
  __builtin_amdgcn_global_load_lds((const __attribute__((address_space(1))) void*)(gp), \
                                   (__attribute__((address_space(3))) void*)(lp), 16, 0, 0)

#define SB() __builtin_amdgcn_sched_barrier(0)
#define BARRIER() __builtin_amdgcn_s_barrier()
#define WAIT_VM6() asm volatile("s_waitcnt vmcnt(6)" ::: "memory")
#define WAIT_VM0() asm volatile("s_waitcnt vmcnt(0)" ::: "memory")
#define NOWAIT() ((void)0)

// ------- merged convert: blocks [0,2048) do mat1 int32->int8 (same layout);
//         blocks [2048,6144) do mat2 [K][N] int32 -> [N][K] int8 transpose --
__global__ __launch_bounds__(256) void cvt_kernel(const int* __restrict__ mat1,
                                                  char* __restrict__ A8,
                                                  const int* __restrict__ mat2,
                                                  char* __restrict__ B8T) {
  __shared__ char tile[64][68];
  if (blockIdx.x < 2048) {
    const int n4 = MK * MK / 4;
    int idx = blockIdx.x * 256 + threadIdx.x;
    const int stride = 2048 * 256;
    for (int i = idx; i < n4; i += stride) {
      int4 v = ((const int4*)mat1)[i];
      char4 c;
      c.x = (char)v.x; c.y = (char)v.y; c.z = (char)v.z; c.w = (char)v.w;
      ((char4*)A8)[i] = c;
    }
  } else {
    const int bid = blockIdx.x - 2048;
    const int t = threadIdx.x;
    const int n0 = (bid & 63) * 64, k0 = (bid >> 6) * 64;
#pragma unroll
    for (int r = 0; r < 16; ++r) {
      int k = k0 + r * 4 + (t >> 6);
      int n = n0 + (t & 63);
      tile[t & 63][r * 4 + (t >> 6)] = (char)mat2[(size_t)k * MK + n];
    }
    __syncthreads();
#pragma unroll
    for (int w = 0; w < 4; ++w) {
      int nl = w * 16 + (t >> 4);
      int kl = (t & 15) * 4;
      char4 c = *(const char4*)&tile[nl][kl];
      *(char4*)(B8T + (size_t)(n0 + nl) * MK + k0 + kl) = c;
    }
  }
}

// ---------------- i8 MFMA GEMM, 256x128 tile, 32x32x32 MFMA ----------------
// R15: TWO INDEPENDENT BLOCKS PER CU. R13's residual (~19us loop gap over the
// ~37us LDS-pipe floor + ~21us fully-exposed HBM epilogue) shares one root:
// all waves on a CU were one barrier domain -- SIMD-mates stall together at
// each of 64 barriers, and the end-of-kernel epilogue has no co-resident
// compute to hide under. Restructure: 256x128 tile, 256-thr block (4 waves,
// 2x2 grid, per-wave 128x64 -> acc[4][2] and the proven 6-read/8-MFMA phase
// shape UNCHANGED), grid 512, TRIPLE-buffered BK=64 (3 x 24KB = 72KB -> 2
// blocks/CU; each SIMD hosts 1 wave from each block, so when block X stalls
// at its barrier block Y issues MFMAs (m114), and the earlier finisher's
// epilogue hides under the other's K-loop). Triple buffering keeps the R8
// drain invariant at 1-region-per-tile granularity: stage tile t+2 during
// tile t; region-end vmcnt(6) leaves this region's 6 ops, drains tile t+1's
// (issued a full region earlier) -- no young-load waits (R9's failure mode).
// Region structure = R13: 6 kk0-reads + 2 hoisted kk1-critical reads, stages
// spread 3+3 mid-region, B-major MFMAs, 64 barriers.
// LDS: A 3 bufs x 16KB at 0, B 3 bufs x 8KB at 49152; unit = 32row x 32K
// 1024B block with the R4-verified 0-conflict XOR slot layout:
// slot = (2*khalf + (row>>4)) ^ ((row&15)>>1 & 3).
// XCD swizzle: 8m x 8n rectangle per XCD (A 8MB + B 4MB unique, as before).
// REVERT RULE: gemm > 77us or occupancy < ~19% (2nd block not resident) ->
// back to R13, declare plateau.
__global__ __launch_bounds__(256, 2) void gemm_i8_kernel(const char* __restrict__ A8,
                                                         const char* __restrict__ B8T,
                                                         const int* __restrict__ inp,
                                                         float* __restrict__ out) {
  extern __shared__ char lds[];
  const int tid = threadIdx.x;
  const int wg = blockIdx.x;
  // XCD-aware rectangle swizzle, bijective over 512 = 16m x 32n tiles:
  // xcd = wg&7 owns m-groups [(xcd>>2)*8,+8) x n-groups [(xcd&3)*8,+8).
  const int xcd = wg & 7, loc = wg >> 3;  // loc in [0,64)
  const int m0 = (((xcd >> 2) << 3) + (loc >> 3)) << 8;   // 16 m-tiles of 256
  const int n0 = (((xcd & 3) << 3) + (loc & 7)) << 7;     // 32 n-tiles of 128

  const int lane = tid & 63, wid = tid >> 6;
  const int wr = wid >> 1, wc = wid & 1;   // 2x2 wave grid
  const int rl = lane & 31;
  const int khalf = lane >> 5;

  // per-lane LDS read base: R2/R4's measured-0-conflict pattern
  const int r15 = lane & 15;
  const int slotr = (lane >> 4) ^ ((r15 >> 1) & 3);
  const char* pAr = lds + wr * 8192 + r15 * 64 + slotr * 16;           // wr: 4 mb
  const char* pBr = lds + 49152 + wc * 4096 + r15 * 64 + slotr * 16;   // wc: 2 nb

  // staging decode (256 thr): thread t feeds A chunks t+{0,256,512,768} and
  // B chunks t+{0,256}. chunk c = [mbg:x][kk:2][r15:16][slot:4] of 16B.
  const int sblk = tid >> 7;              // 0/1
  const int skk = (tid >> 6) & 1;
  const int sr15 = (tid >> 2) & 15;
  const int sslot = tid & 3;
  const int sx = sslot ^ ((sr15 >> 1) & 3);
  const int srow = sblk * 32 + (sx & 1) * 16 + sr15;      // +64 per extra op
  const int skb = skk * 32 + (sx >> 1) * 16;              // K-byte in [0,64)
  const char* pA = A8 + (size_t)(m0 + srow) * MK + skb;
  const char* pB = B8T + (size_t)(n0 + srow) * MK + skb;
  char* ldswA = lds + (tid & ~63) * 16;            // + SB*16384 + j*4096
  char* ldswB = lds + 49152 + (tid & ~63) * 16;    // + SB*8192  + j*4096

// stage halves: P0 = A rows {srow, +64} + B cols {srow}; P1 = A {+128,+192}
// + B {+64}. 3 VMEM ops each, spread across the region's two MFMA windows.
#define STAGE_P0(SB_, TN_) do {                                                   \
    const char* sa_ = pA + (TN_)*64;                                              \
    GLOAD_LDS16(sa_,                   ldswA + ((SB_)*16384));                    \
    GLOAD_LDS16(sa_ + (size_t)64 * MK, ldswA + ((SB_)*16384 + 4096));             \
    GLOAD_LDS16(pB + (TN_)*64,         ldswB + ((SB_)*8192));                     \
  } while (0)
#define STAGE_P1(SB_, TN_) do {                                                   \
    const char* sa_ = pA + (TN_)*64;                                              \
    GLOAD_LDS16(sa_ + (size_t)128 * MK, ldswA + ((SB_)*16384 + 8192));            \
    GLOAD_LDS16(sa_ + (size_t)192 * MK, ldswA + ((SB_)*16384 + 12288));           \
    GLOAD_LDS16(pB + (TN_)*64 + (size_t)64 * MK, ldswB + ((SB_)*8192 + 4096));    \
  } while (0)

#define AOFF(S_, KK_, MB_) ((S_)*16384 + (MB_)*2048 + (KK_)*1024)
#define BOFF(S_, KK_, NB_) ((S_)*8192 + (NB_)*2048 + (KK_)*1024)

// one region = one K-tile (BK=64 = 2 kk-steps), R13 structure:
// [6 kk0 reads + bg0/ag0 hoist][STAGE_P0][8 f-MFMAs][4 reads][STAGE_P1]
// [8 g-MFMAs][SB vmcnt barrier SB]. Compiler handles lgkmcnt.
#define REGION(RB_, SB_, TN_, DOST_, VMW_, DOSYNC_) do {                          \
    bf0 = *(const v4i*)(pBr + BOFF(RB_, 0, 0));                                   \
    af0 = *(const v4i*)(pAr + AOFF(RB_, 0, 0));                                   \
    af1 = *(const v4i*)(pAr + AOFF(RB_, 0, 1));                                   \
    af2 = *(const v4i*)(pAr + AOFF(RB_, 0, 2));                                   \
    af3 = *(const v4i*)(pAr + AOFF(RB_, 0, 3));                                   \
    bf1 = *(const v4i*)(pBr + BOFF(RB_, 0, 1));                                   \
    bg0 = *(const v4i*)(pBr + BOFF(RB_, 1, 0));                                   \
    ag0 = *(const v4i*)(pAr + AOFF(RB_, 1, 0));                                   \
    if (DOST_) STAGE_P0(SB_, TN_);                                                \
    __builtin_amdgcn_s_setprio(1);                                                \
    acc[0][0] = MFMA32(af0, bf0, acc[0][0]); acc[1][0] = MFMA32(af1, bf0, acc[1][0]); \
    acc[2][0] = MFMA32(af2, bf0, acc[2][0]); acc[3][0] = MFMA32(af3, bf0, acc[3][0]); \
    acc[0][1] = MFMA32(af0, bf1, acc[0][1]); acc[1][1] = MFMA32(af1, bf1, acc[1][1]); \
    acc[2][1] = MFMA32(af2, bf1, acc[2][1]); acc[3][1] = MFMA32(af3, bf1, acc[3][1]); \
    __builtin_amdgcn_s_setprio(0);                                                \
    ag1 = *(const v4i*)(pAr + AOFF(RB_, 1, 1));                                   \
    ag2 = *(const v4i*)(pAr + AOFF(RB_, 1, 2));                                   \
    ag3 = *(const v4i*)(pAr + AOFF(RB_, 1, 3));                                   \
    bg1 = *(const v4i*)(pBr + BOFF(RB_, 1, 1));                                   \
    if (DOST_) STAGE_P1(SB_, TN_);                                                \
    __builtin_amdgcn_s_setprio(1);                                                \
    acc[0][0] = MFMA32(ag0, bg0, acc[0][0]); acc[1][0] = MFMA32(ag1, bg0, acc[1][0]); \
    acc[2][0] = MFMA32(ag2, bg0, acc[2][0]); acc[3][0] = MFMA32(ag3, bg0, acc[3][0]); \
    acc[0][1] = MFMA32(ag0, bg1, acc[0][1]); acc[1][1] = MFMA32(ag1, bg1, acc[1][1]); \
    acc[2][1] = MFMA32(ag2, bg1, acc[2][1]); acc[3][1] = MFMA32(ag3, bg1, acc[3][1]); \
    __builtin_amdgcn_s_setprio(0);                                                \
    if (DOSYNC_) { SB(); VMW_; BARRIER(); SB(); }                                 \
  } while (0)

  v16i acc[4][2];
#pragma unroll
  for (int m = 0; m < 4; ++m)
#pragma unroll
    for (int n = 0; n < 2; ++n)
#pragma unroll
      for (int i = 0; i < 16; ++i) acc[m][n][i] = 0;
  v4i af0, af1, af2, af3, bf0, bf1;
  v4i ag0, ag1, ag2, ag3, bg0, bg1;

  // prologue: stage tile0 -> buf0 and tile1 -> buf1 (12 ops); vmcnt(6)
  // drains tile0's 6, leaves tile1's in flight; sync.
  STAGE_P0(0, 0); STAGE_P1(0, 0); STAGE_P0(1, 1); STAGE_P1(1, 1);
  SB(); WAIT_VM6(); BARRIER(); SB();

  // 64 K-tiles; tile t reads buf t%3, stages tile t+2 into buf (t+2)%3.
#pragma unroll 1
  for (int it = 0; it < 20; ++it) {
    REGION(0, 2, 3 * it + 2, 1, WAIT_VM6(), 1);
    REGION(1, 0, 3 * it + 3, 1, WAIT_VM6(), 1);
    REGION(2, 1, 3 * it + 4, 1, WAIT_VM6(), 1);
  }
  REGION(0, 2, 62, 1, WAIT_VM6(), 1);   // tile 60, stages 62
  REGION(1, 0, 63, 1, WAIT_VM6(), 1);   // tile 61, stages 63
  REGION(2, 0, 0, 0, WAIT_VM0(), 1);    // tile 62, no stage; drain 63's (old)
  REGION(0, 0, 0, 0, NOWAIT(), 0);      // tile 63, no sync after

  // epilogue: 32x32 C/D layout col=lane&31, row=(reg&3)+8*(reg>>2)+4*khalf
#pragma unroll
  for (int mb = 0; mb < 4; ++mb) {
#pragma unroll
    for (int nb = 0; nb < 2; ++nb) {
      const int col = n0 + wc * 64 + nb * 32 + rl;
      const int row0 = m0 + wr * 128 + mb * 32 + 4 * khalf;
#pragma unroll
      for (int r = 0; r < 16; ++r) {
        const int row = row0 + (r & 3) + 8 * (r >> 2);
        const size_t idx = (size_t)row * MK + col;
        const int v = acc[mb][nb][r] + __builtin_nontemporal_load(inp + idx);
        __builtin_nontemporal_store((float)v, out + idx);
      }
    }
  }
}

// ---------------- fallback (only if ws too small): naive tiled int32 -------
__global__ void fallback_kernel(const int* __restrict__ mat1, const int* __restrict__ mat2,
                                const int* __restrict__ inp, float* __restrict__ out) {
  __shared__ int As[16][16], Bs[16][17];
  int tx = threadIdx.x, ty = threadIdx.y;
  int row = blockIdx.y * 16 + ty, col = blockIdx.x * 16 + tx;
  int acc = 0;
  for (int kt = 0; kt < MK / 16; ++kt) {
    As[ty][tx] = mat1[(size_t)row * MK + kt * 16 + tx];
    Bs[ty][tx] = mat2[(size_t)(kt * 16 + ty) * MK + col];
    __syncthreads();
#pragma unroll
    for (int k = 0; k < 16; ++k) acc += As[ty][k] * Bs[k][tx];
    __syncthreads();
  }
  size_t idx = (size_t)row * MK + col;
  out[idx] = (float)(acc + inp[idx]);
}

extern "C" void kernel_launch(void* const* d_in, const int* in_sizes, int n_in,
                              void* d_out, int out_size, void* d_ws, size_t ws_size,
                              hipStream_t stream) {
  const int* inp = (const int*)d_in[0];
  const int* mat1 = (const int*)d_in[1];
  const int* mat2 = (const int*)d_in[2];
  float* out = (float*)d_out;

  const size_t need = 2 * (size_t)MK * MK;
  if (ws_size >= need) {
    char* A8 = (char*)d_ws;
    char* B8T = A8 + (size_t)MK * MK;
    cvt_kernel<<<6144, 256, 0, stream>>>(mat1, A8, mat2, B8T);
    (void)hipFuncSetAttribute((const void*)gemm_i8_kernel,
                              hipFuncAttributeMaxDynamicSharedMemorySize, 73728);
    gemm_i8_kernel<<<512, 256, 73728, stream>>>(A8, B8T, inp, out);
  } else {
    dim3 blk(16, 16), grd(MK / 16, MK / 16);
    fallback_kernel<<<grd, blk, 0, stream>>>(mat1, mat2, inp, out);
  }
}

// Round 11
// 100.590 us; speedup vs baseline: 1.1300x; 1.1300x over previous
//
#include <hip/hip_runtime.h>

#define MK 4096
#define BK 128

typedef int v4i __attribute__((ext_vector_type(4)));
typedef int v16i __attribute__((ext_vector_type(16)));

#define MFMA32(a, b, c) __builtin_amdgcn_mfma_i32_32x32x32_i8(a, b, c, 0, 0, 0)

#define GLOAD_LDS16(gp, lp) \
  __builtin_amdgcn_global_load_lds((const __attribute__((address_space(1))) void*)(gp), \
                                   (__attribute__((address_space(3))) void*)(lp), 16, 0, 0)

#define SB() __builtin_amdgcn_sched_barrier(0)
#define BARRIER() __builtin_amdgcn_s_barrier()
#define WAIT_VM4() asm volatile("s_waitcnt vmcnt(4)" ::: "memory")
#define WAIT_VM0() asm volatile("s_waitcnt vmcnt(0)" ::: "memory")
#define NOWAIT() ((void)0)

// ------- merged convert: blocks [0,2048) do mat1 int32->int8 (same layout);
//         blocks [2048,6144) do mat2 [K][N] int32 -> [N][K] int8 transpose --
__global__ __launch_bounds__(256) void cvt_kernel(const int* __restrict__ mat1,
                                                  char* __restrict__ A8,
                                                  const int* __restrict__ mat2,
                                                  char* __restrict__ B8T) {
  __shared__ char tile[64][68];
  if (blockIdx.x < 2048) {
    const int n4 = MK * MK / 4;
    int idx = blockIdx.x * 256 + threadIdx.x;
    const int stride = 2048 * 256;
    for (int i = idx; i < n4; i += stride) {
      int4 v = ((const int4*)mat1)[i];
      char4 c;
      c.x = (char)v.x; c.y = (char)v.y; c.z = (char)v.z; c.w = (char)v.w;
      ((char4*)A8)[i] = c;
    }
  } else {
    const int bid = blockIdx.x - 2048;
    const int t = threadIdx.x;
    const int n0 = (bid & 63) * 64, k0 = (bid >> 6) * 64;
#pragma unroll
    for (int r = 0; r < 16; ++r) {
      int k = k0 + r * 4 + (t >> 6);
      int n = n0 + (t & 63);
      tile[t & 63][r * 4 + (t >> 6)] = (char)mat2[(size_t)k * MK + n];
    }
    __syncthreads();
#pragma unroll
    for (int w = 0; w < 4; ++w) {
      int nl = w * 16 + (t >> 4);
      int kl = (t & 15) * 4;
      char4 c = *(const char4*)&tile[nl][kl];
      *(char4*)(B8T + (size_t)(n0 + nl) * MK + k0 + kl) = c;
    }
  }
}

// ---------------- i8 MFMA GEMM, 256x256 tile, 32x32x32 MFMA ----------------
// R16 = R13 EXACT REVERT (best measured: gemm 77.2-77.7us, total 100.4us).
// Ledger of structural attempts on this problem:
//   R6  inp L3-prefetch            -> +14us (FIFO inherits HBM latency, L2 pollution)
//   R7  stage-early clustering     -> +5us  (write-back collides with ds_read storm)
//   R9  per-tile barrier vmcnt(0)  -> +4us  (drain covers young loads)
//   R10 per-tile + stages in p0-1  -> +9us  (clustered write-back, same drain issue)
//   R12 wave-skewed kk order       -> neutral (changes WHAT not WHEN)
//   R13 partial 2-read hoist       -> -2us  WIN (validated pipeline theory)
//   R14 full 12-read hoist         -> +7us  (doubled post-barrier LDS storm)
//   R15 2 blocks/CU, 256x128, BK64 -> +16us (same 8 waves/CU, 1.5x staging, short cover)
// Remaining decomposition: MFMA floor 31us; LDS-pipe floor ~37us; epilogue
// ~21us at measured 6.1 TB/s HBM (roofline); cvt ~22us at HBM floor. The
// ~19us main-loop overlap residual resisted 6 independent attack angles at
// the binding constraints: 2 waves/SIMD, 252/256 VGPR, single barrier domain.
// Structure: 2 barriers per K-tile (one per half), each preceded by per-wave
// vmcnt(4) that only waits on loads >=1 half (~1200cyc) old; stages embedded
// mid-phase (after reads, before MFMAs); partial hoist of next-phase critical
// pair (bg0/ag0); bf0-first reads + B-major MFMAs; 4x8 XCD rectangle swizzle.
// LDS half layout (16 KiB): [blk:8][kk:2][r15:16][slot:4][16B],
// slot = (2*khalf + (row>>4)) ^ ((row&15)>>1 & 3)  (R4-verified 0-conflict).
__global__ __launch_bounds__(512, 2) void gemm_i8_kernel(const char* __restrict__ A8,
                                                         const char* __restrict__ B8T,
                                                         const int* __restrict__ inp,
                                                         float* __restrict__ out) {
  extern __shared__ char lds[];
  const int tid = threadIdx.x;
  const int wg = blockIdx.x;
  // XCD-aware 4x8 rectangle swizzle, bijective: xcd = wg&7 owns row-groups
  // [(xcd>>1)*4, +4) x col-groups [(xcd&1)*8, +8).
  const int xcd = wg & 7, loc = wg >> 3;
  const int m0 = (((xcd >> 1) << 2) + (loc >> 3)) << 8;
  const int n0 = (((xcd & 1) << 3) + (loc & 7)) << 8;

  const int lane = tid & 63, wid = tid >> 6;
  const int wr = wid >> 2, wc = wid & 3;
  const int rl = lane & 31;
  const int khalf = lane >> 5;

  // per-lane LDS read base: R2/R4's measured-0-conflict pattern
  const int r15 = lane & 15;
  const int slotr = (lane >> 4) ^ ((r15 >> 1) & 3);
  const char* pAr = lds + wr * 8192 + r15 * 64 + slotr * 16;
  const char* pBr = lds + 65536 + wc * 4096 + r15 * 64 + slotr * 16;

  // staging decode: thread t feeds LDS chunk idx=t (and idx+512 = +4 blks)
  const int sblk = tid >> 7;
  const int skk = (tid >> 6) & 1;
  const int sr15 = (tid >> 2) & 15;
  const int sslot = tid & 3;
  const int sx = sslot ^ ((sr15 >> 1) & 3);
  const int srow = sblk * 32 + (sx & 1) * 16 + sr15;
  const int skb = skk * 32 + (sx >> 1) * 16;
  const char* pA = A8 + (size_t)(m0 + srow) * MK + skb;
  const char* pB = B8T + (size_t)(n0 + srow) * MK + skb;
  char* ldsw = lds + (tid & ~63) * 16;  // wave-uniform dest base (+hw lane*16)

#define STAGE_A_(NB_, H_, TN_) do {                                               \
    const char* s_ = pA + (TN_)*BK + (H_)*64;                                     \
    GLOAD_LDS16(s_,                    ldsw + ((NB_)*32768 + (H_)*16384));        \
    GLOAD_LDS16(s_ + (size_t)128 * MK, ldsw + ((NB_)*32768 + (H_)*16384 + 8192)); \
  } while (0)
#define STAGE_B_(NB_, H_, TN_) do {                                               \
    const char* s_ = pB + (TN_)*BK + (H_)*64;                                     \
    GLOAD_LDS16(s_,                    ldsw + (65536 + (NB_)*32768 + (H_)*16384)); \
    GLOAD_LDS16(s_ + (size_t)128 * MK, ldsw + (65536 + (NB_)*32768 + (H_)*16384 + 8192)); \
  } while (0)

#define AOFF(B_, KK_, MB_) ((B_)*32768 + ((KK_) >> 1) * 16384 + (MB_)*2048 + ((KK_)&1) * 1024)
#define BOFF(B_, KK_, NB_) ((B_)*32768 + ((KK_) >> 1) * 16384 + (NB_)*2048 + ((KK_)&1) * 1024)

// one region = one half-tile (2 kk-steps). Phase-0: 6 reads (bf0-first),
// +2 hoisted phase-1 critical reads (bg0, ag0), STAGE_A, 8 B-major MFMAs.
// Phase-1: remaining 4 reads, STAGE_B, 8 MFMAs. Then the region's ONLY
// sync: SB + vmcnt + barrier + SB. Compiler handles lgkmcnt.
#define REGION(B_, H_, TN_, DOST_, VMW_, DOSYNC_) do {                            \
    bf0 = *(const v4i*)(pBr + BOFF(B_, 2*(H_), 0));                               \
    af0 = *(const v4i*)(pAr + AOFF(B_, 2*(H_), 0));                               \
    af1 = *(const v4i*)(pAr + AOFF(B_, 2*(H_), 1));                               \
    af2 = *(const v4i*)(pAr + AOFF(B_, 2*(H_), 2));                               \
    af3 = *(const v4i*)(pAr + AOFF(B_, 2*(H_), 3));                               \
    bf1 = *(const v4i*)(pBr + BOFF(B_, 2*(H_), 1));                               \
    bg0 = *(const v4i*)(pBr + BOFF(B_, 2*(H_) + 1, 0));                           \
    ag0 = *(const v4i*)(pAr + AOFF(B_, 2*(H_) + 1, 0));                           \
    if (DOST_) STAGE_A_((B_) ^ 1, H_, TN_);                                       \
    __builtin_amdgcn_s_setprio(1);                                                \
    acc[0][0] = MFMA32(af0, bf0, acc[0][0]); acc[1][0] = MFMA32(af1, bf0, acc[1][0]); \
    acc[2][0] = MFMA32(af2, bf0, acc[2][0]); acc[3][0] = MFMA32(af3, bf0, acc[3][0]); \
    acc[0][1] = MFMA32(af0, bf1, acc[0][1]); acc[1][1] = MFMA32(af1, bf1, acc[1][1]); \
    acc[2][1] = MFMA32(af2, bf1, acc[2][1]); acc[3][1] = MFMA32(af3, bf1, acc[3][1]); \
    __builtin_amdgcn_s_setprio(0);                                                \
    ag1 = *(const v4i*)(pAr + AOFF(B_, 2*(H_) + 1, 1));                           \
    ag2 = *(const v4i*)(pAr + AOFF(B_, 2*(H_) + 1, 2));                           \
    ag3 = *(const v4i*)(pAr + AOFF(B_, 2*(H_) + 1, 3));                           \
    bg1 = *(const v4i*)(pBr + BOFF(B_, 2*(H_) + 1, 1));                           \
    if (DOST_) STAGE_B_((B_) ^ 1, H_, TN_);                                       \
    __builtin_amdgcn_s_setprio(1);                                                \
    acc[0][0] = MFMA32(ag0, bg0, acc[0][0]); acc[1][0] = MFMA32(ag1, bg0, acc[1][0]); \
    acc[2][0] = MFMA32(ag2, bg0, acc[2][0]); acc[3][0] = MFMA32(ag3, bg0, acc[3][0]); \
    acc[0][1] = MFMA32(ag0, bg1, acc[0][1]); acc[1][1] = MFMA32(ag1, bg1, acc[1][1]); \
    acc[2][1] = MFMA32(ag2, bg1, acc[2][1]); acc[3][1] = MFMA32(ag3, bg1, acc[3][1]); \
    __builtin_amdgcn_s_setprio(0);                                                \
    if (DOSYNC_) { SB(); VMW_; BARRIER(); SB(); }                                 \
  } while (0)

  v16i acc[4][2];
#pragma unroll
  for (int m = 0; m < 4; ++m)
#pragma unroll
    for (int n = 0; n < 2; ++n)
#pragma unroll
      for (int i = 0; i < 16; ++i) acc[m][n][i] = 0;
  v4i af0, af1, af2, af3, bf0, bf1;
  v4i ag0, ag1, ag2, ag3, bg0, bg1;

  // prologue: stage tile 0 -> buf0 (8 loads), drain h0, sync
  STAGE_A_(0, 0, 0); STAGE_B_(0, 0, 0); STAGE_A_(0, 1, 0); STAGE_B_(0, 1, 0);
  WAIT_VM4(); BARRIER(); SB();

#pragma unroll 1
  for (int it = 0; it < 15; ++it) {
    REGION(0, 0, 2 * it + 1, 1, WAIT_VM4(), 1);
    REGION(0, 1, 2 * it + 1, 1, WAIT_VM4(), 1);
    REGION(1, 0, 2 * it + 2, 1, WAIT_VM4(), 1);
    REGION(1, 1, 2 * it + 2, 1, WAIT_VM4(), 1);
  }
  REGION(0, 0, 31, 1, WAIT_VM4(), 1);
  REGION(0, 1, 31, 1, WAIT_VM4(), 1);
  // tile 31: no staging; region h0 must drain h1's loads before h1 reads
  REGION(1, 0, 0, 0, WAIT_VM0(), 1);
  REGION(1, 1, 0, 0, NOWAIT(), 0);  // last half, no sync needed after

  // epilogue: 32x32 C/D layout col=lane&31, row=(reg&3)+8*(reg>>2)+4*khalf
#pragma unroll
  for (int mb = 0; mb < 4; ++mb) {
#pragma unroll
    for (int nb = 0; nb < 2; ++nb) {
      const int col = n0 + wc * 64 + nb * 32 + rl;
      const int row0 = m0 + wr * 128 + mb * 32 + 4 * khalf;
#pragma unroll
      for (int r = 0; r < 16; ++r) {
        const int row = row0 + (r & 3) + 8 * (r >> 2);
        const size_t idx = (size_t)row * MK + col;
        const int v = acc[mb][nb][r] + __builtin_nontemporal_load(inp + idx);
        __builtin_nontemporal_store((float)v, out + idx);
      }
    }
  }
}

// ---------------- fallback (only if ws too small): naive tiled int32 -------
__global__ void fallback_kernel(const int* __restrict__ mat1, const int* __restrict__ mat2,
                                const int* __restrict__ inp, float* __restrict__ out) {
  __shared__ int As[16][16], Bs[16][17];
  int tx = threadIdx.x, ty = threadIdx.y;
  int row = blockIdx.y * 16 + ty, col = blockIdx.x * 16 + tx;
  int acc = 0;
  for (int kt = 0; kt < MK / 16; ++kt) {
    As[ty][tx] = mat1[(size_t)row * MK + kt * 16 + tx];
    Bs[ty][tx] = mat2[(size_t)(kt * 16 + ty) * MK + col];
    __syncthreads();
#pragma unroll
    for (int k = 0; k < 16; ++k) acc += As[ty][k] * Bs[k][tx];
    __syncthreads();
  }
  size_t idx = (size_t)row * MK + col;
  out[idx] = (float)(acc + inp[idx]);
}

extern "C" void kernel_launch(void* const* d_in, const int* in_sizes, int n_in,
                              void* d_out, int out_size, void* d_ws, size_t ws_size,
                              hipStream_t stream) {
  const int* inp = (const int*)d_in[0];
  const int* mat1 = (const int*)d_in[1];
  const int* mat2 = (const int*)d_in[2];
  float* out = (float*)d_out;

  const size_t need = 2 * (size_t)MK * MK;
  if (ws_size >= need) {
    char* A8 = (char*)d_ws;
    char* B8T = A8 + (size_t)MK * MK;
    cvt_kernel<<<6144, 256, 0, stream>>>(mat1, A8, mat2, B8T);
    (void)hipFuncSetAttribute((const void*)gemm_i8_kernel,
                              hipFuncAttributeMaxDynamicSharedMemorySize, 131072);
    gemm_i8_kernel<<<256, 512, 131072, stream>>>(A8, B8T, inp, out);
  } else {
    dim3 blk(16, 16), grd(MK / 16, MK / 16);
    fallback_kernel<<<grd, blk, 0, stream>>>(mat1, mat2, inp, out);
  }
}

// Round 12
// 95.047 us; speedup vs baseline: 1.1959x; 1.0583x over previous
//
#include <hip/hip_runtime.h>

#define MK 4096
#define BK 128

typedef int v4i __attribute__((ext_vector_type(4)));
typedef int v16i __attribute__((ext_vector_type(16)));

#define MFMA32(a, b, c) __builtin_amdgcn_mfma_i32_32x32x32_i8(a, b, c, 0, 0, 0)

#define GLOAD_LDS16(gp, lp) \
  __builtin_amdgcn_global_load_lds((const __attribute__((address_space(1))) void*)(gp), \
                                   (__attribute__((address_space(3))) void*)(lp), 16, 0, 0)

#define SB() __builtin_amdgcn_sched_barrier(0)
#define BARRIER() __builtin_amdgcn_s_barrier()
#define WAIT_VM4() asm volatile("s_waitcnt vmcnt(4)" ::: "memory")
#define WAIT_VM6() asm volatile("s_waitcnt vmcnt(6)" ::: "memory")
#define WAIT_VM0() asm volatile("s_waitcnt vmcnt(0)" ::: "memory")
#define NOWAIT() ((void)0)

// ------- merged convert: blocks [0,2048) do mat1 int32->int8 (same layout);
//         blocks [2048,6144) do mat2 [K][N] int32 -> [N][K] int8 transpose --
__global__ __launch_bounds__(256) void cvt_kernel(const int* __restrict__ mat1,
                                                  char* __restrict__ A8,
                                                  const int* __restrict__ mat2,
                                                  char* __restrict__ B8T) {
  __shared__ char tile[64][68];
  if (blockIdx.x < 2048) {
    const int n4 = MK * MK / 4;
    int idx = blockIdx.x * 256 + threadIdx.x;
    const int stride = 2048 * 256;
    for (int i = idx; i < n4; i += stride) {
      int4 v = ((const int4*)mat1)[i];
      char4 c;
      c.x = (char)v.x; c.y = (char)v.y; c.z = (char)v.z; c.w = (char)v.w;
      ((char4*)A8)[i] = c;
    }
  } else {
    const int bid = blockIdx.x - 2048;
    const int t = threadIdx.x;
    const int n0 = (bid & 63) * 64, k0 = (bid >> 6) * 64;
#pragma unroll
    for (int r = 0; r < 16; ++r) {
      int k = k0 + r * 4 + (t >> 6);
      int n = n0 + (t & 63);
      tile[t & 63][r * 4 + (t >> 6)] = (char)mat2[(size_t)k * MK + n];
    }
    __syncthreads();
#pragma unroll
    for (int w = 0; w < 4; ++w) {
      int nl = w * 16 + (t >> 4);
      int kl = (t & 15) * 4;
      char4 c = *(const char4*)&tile[nl][kl];
      *(char4*)(B8T + (size_t)(n0 + nl) * MK + k0 + kl) = c;
    }
  }
}

// ---------------- i8 MFMA GEMM, 256x256 tile, 32x32x32 MFMA ----------------
// R17 = R13/R16 structure + INP READ FOLDED INTO THE K-LOOP. The epilogue's
// serialized 64MB inp read (~10us HBM-bound) moves into the main loop, which
// runs at only ~0.6 TB/s (5+ TB/s headroom). Mechanism (and why R6 failed but
// this works): region r (COMPILE-TIME index via full 64-region unroll -- rule
// #20 forbids runtime acc indices) issues 2 dword loads of inp pair r =
// (mb=r>>4, rr=r&15) at region START (cover ~1500cyc), and at region END
// (after its MFMAs, ~2300cyc after issue) adds pair r-1 into acc[mb][0/1][rr]
// (2 VALU). FIFO: each region = 6 VMEM (2 inp + 4 stages); region-end wait =
// vmcnt(6): leaves this region's 6, drains the previous region's 6 -- stages
// publish on the R13 cadence (>=1 region old), inp pairs complete 1 region
// after issue, NO barrier-adjacent wait ever covers a young HBM load (the R6
// failure). Compiler's own counted wait before the adds drains 2 ops ~2
// regions old -> no stall. Epilogue = convert+store only (~64MB, ~10us).
// Kept: partial bg0/ag0 hoist (R13 win), stages embedded mid-phase, bf0-first
// B-major MFMAs, 4x8 XCD rectangle swizzle, merged cvt.
// Ledger: R6 prefetch +14; R7 stage-early +5; R9/R10 tile-barrier +4/+9;
// R12 skew 0; R13 hoist -2 WIN; R14 full hoist +7; R15 2-block +16.
// REVERT RULE: gemm >= 77.5us, VGPR > 200, or scratch -> R16, declare plateau.
// LDS half layout (16 KiB): [blk:8][kk:2][r15:16][slot:4][16B],
// slot = (2*khalf + (row>>4)) ^ ((row&15)>>1 & 3)  (R4-verified 0-conflict).
__global__ __launch_bounds__(512, 2) void gemm_i8_kernel(const char* __restrict__ A8,
                                                         const char* __restrict__ B8T,
                                                         const int* __restrict__ inp,
                                                         float* __restrict__ out) {
  extern __shared__ char lds[];
  const int tid = threadIdx.x;
  const int wg = blockIdx.x;
  // XCD-aware 4x8 rectangle swizzle, bijective: xcd = wg&7 owns row-groups
  // [(xcd>>1)*4, +4) x col-groups [(xcd&1)*8, +8).
  const int xcd = wg & 7, loc = wg >> 3;
  const int m0 = (((xcd >> 1) << 2) + (loc >> 3)) << 8;
  const int n0 = (((xcd & 1) << 3) + (loc & 7)) << 8;

  const int lane = tid & 63, wid = tid >> 6;
  const int wr = wid >> 2, wc = wid & 3;
  const int rl = lane & 31;
  const int khalf = lane >> 5;

  // per-lane LDS read base: R2/R4's measured-0-conflict pattern
  const int r15 = lane & 15;
  const int slotr = (lane >> 4) ^ ((r15 >> 1) & 3);
  const char* pAr = lds + wr * 8192 + r15 * 64 + slotr * 16;
  const char* pBr = lds + 65536 + wc * 4096 + r15 * 64 + slotr * 16;

  // staging decode: thread t feeds LDS chunk idx=t (and idx+512 = +4 blks)
  const int sblk = tid >> 7;
  const int skk = (tid >> 6) & 1;
  const int sr15 = (tid >> 2) & 15;
  const int sslot = tid & 3;
  const int sx = sslot ^ ((sr15 >> 1) & 3);
  const int srow = sblk * 32 + (sx & 1) * 16 + sr15;
  const int skb = skk * 32 + (sx >> 1) * 16;
  const char* pA = A8 + (size_t)(m0 + srow) * MK + skb;
  const char* pB = B8T + (size_t)(n0 + srow) * MK + skb;
  char* ldsw = lds + (tid & ~63) * 16;  // wave-uniform dest base (+hw lane*16)

  // inp per-thread bases: pair p covers acc[p>>4][nb][p&15] for nb=0,1.
  const int* pI0 = inp + (size_t)(m0 + wr * 128 + 4 * khalf) * MK + (n0 + wc * 64 + rl);
  const int* pI1 = pI0 + 32;
// element offset of pair P_'s row: (mb*32 + (rr&3) + 8*(rr>>2)) rows
#define IOFF(P_) (((((P_) >> 4) * 32) + (((P_) & 15) & 3) + 8 * (((P_) & 15) >> 2)) * MK)

#define STAGE_A_(NB_, H_, TN_) do {                                               \
    const char* s_ = pA + (TN_)*BK + (H_)*64;                                     \
    GLOAD_LDS16(s_,                    ldsw + ((NB_)*32768 + (H_)*16384));        \
    GLOAD_LDS16(s_ + (size_t)128 * MK, ldsw + ((NB_)*32768 + (H_)*16384 + 8192)); \
  } while (0)
#define STAGE_B_(NB_, H_, TN_) do {                                               \
    const char* s_ = pB + (TN_)*BK + (H_)*64;                                     \
    GLOAD_LDS16(s_,                    ldsw + (65536 + (NB_)*32768 + (H_)*16384)); \
    GLOAD_LDS16(s_ + (size_t)128 * MK, ldsw + (65536 + (NB_)*32768 + (H_)*16384 + 8192)); \
  } while (0)

#define AOFF(B_, KK_, MB_) ((B_)*32768 + ((KK_) >> 1) * 16384 + (MB_)*2048 + ((KK_)&1) * 1024)
#define BOFF(B_, KK_, NB_) ((B_)*32768 + ((KK_) >> 1) * 16384 + (NB_)*2048 + ((KK_)&1) * 1024)

// one region = one half-tile (2 kk-steps), region index RIDX_ is a LITERAL.
// [2 inp loads (pair RIDX)][SB][6 reads + bg0/ag0 hoist][STAGE_A][8 f-MFMAs]
// [4 reads][STAGE_B][8 g-MFMAs][add pair RIDX-1 into acc][SB vmcnt barrier SB]
#define REGION(B_, H_, TN_, DOST_, VMW_, DOSYNC_, RIDX_) do {                     \
    ipv[(RIDX_) & 1][0] = pI0[IOFF(RIDX_)];                                       \
    ipv[(RIDX_) & 1][1] = pI1[IOFF(RIDX_)];                                       \
    SB();                                                                         \
    bf0 = *(const v4i*)(pBr + BOFF(B_, 2*(H_), 0));                               \
    af0 = *(const v4i*)(pAr + AOFF(B_, 2*(H_), 0));                               \
    af1 = *(const v4i*)(pAr + AOFF(B_, 2*(H_), 1));                               \
    af2 = *(const v4i*)(pAr + AOFF(B_, 2*(H_), 2));                               \
    af3 = *(const v4i*)(pAr + AOFF(B_, 2*(H_), 3));                               \
    bf1 = *(const v4i*)(pBr + BOFF(B_, 2*(H_), 1));                               \
    bg0 = *(const v4i*)(pBr + BOFF(B_, 2*(H_) + 1, 0));                           \
    ag0 = *(const v4i*)(pAr + AOFF(B_, 2*(H_) + 1, 0));                           \
    if (DOST_) STAGE_A_((B_) ^ 1, H_, TN_);                                       \
    __builtin_amdgcn_s_setprio(1);                                                \
    acc[0][0] = MFMA32(af0, bf0, acc[0][0]); acc[1][0] = MFMA32(af1, bf0, acc[1][0]); \
    acc[2][0] = MFMA32(af2, bf0, acc[2][0]); acc[3][0] = MFMA32(af3, bf0, acc[3][0]); \
    acc[0][1] = MFMA32(af0, bf1, acc[0][1]); acc[1][1] = MFMA32(af1, bf1, acc[1][1]); \
    acc[2][1] = MFMA32(af2, bf1, acc[2][1]); acc[3][1] = MFMA32(af3, bf1, acc[3][1]); \
    __builtin_amdgcn_s_setprio(0);                                                \
    ag1 = *(const v4i*)(pAr + AOFF(B_, 2*(H_) + 1, 1));                           \
    ag2 = *(const v4i*)(pAr + AOFF(B_, 2*(H_) + 1, 2));                           \
    ag3 = *(const v4i*)(pAr + AOFF(B_, 2*(H_) + 1, 3));                           \
    bg1 = *(const v4i*)(pBr + BOFF(B_, 2*(H_) + 1, 1));                           \
    if (DOST_) STAGE_B_((B_) ^ 1, H_, TN_);                                       \
    __builtin_amdgcn_s_setprio(1);                                                \
    acc[0][0] = MFMA32(ag0, bg0, acc[0][0]); acc[1][0] = MFMA32(ag1, bg0, acc[1][0]); \
    acc[2][0] = MFMA32(ag2, bg0, acc[2][0]); acc[3][0] = MFMA32(ag3, bg0, acc[3][0]); \
    acc[0][1] = MFMA32(ag0, bg1, acc[0][1]); acc[1][1] = MFMA32(ag1, bg1, acc[1][1]); \
    acc[2][1] = MFMA32(ag2, bg1, acc[2][1]); acc[3][1] = MFMA32(ag3, bg1, acc[3][1]); \
    __builtin_amdgcn_s_setprio(0);                                                \
    if ((RIDX_) > 0) {                                                            \
      acc[((RIDX_)-1) >> 4][0][((RIDX_)-1) & 15] += ipv[((RIDX_)-1) & 1][0];      \
      acc[((RIDX_)-1) >> 4][1][((RIDX_)-1) & 15] += ipv[((RIDX_)-1) & 1][1];      \
    }                                                                             \
    if (DOSYNC_) { SB(); VMW_; BARRIER(); SB(); }                                 \
  } while (0)

#define QUAD(IT_)                                                                 \
  REGION(0, 0, 2*(IT_) + 1, 1, WAIT_VM6(), 1, 4*(IT_) + 0);                       \
  REGION(0, 1, 2*(IT_) + 1, 1, WAIT_VM6(), 1, 4*(IT_) + 1);                       \
  REGION(1, 0, 2*(IT_) + 2, 1, WAIT_VM6(), 1, 4*(IT_) + 2);                       \
  REGION(1, 1, 2*(IT_) + 2, 1, WAIT_VM6(), 1, 4*(IT_) + 3);

  v16i acc[4][2];
#pragma unroll
  for (int m = 0; m < 4; ++m)
#pragma unroll
    for (int n = 0; n < 2; ++n)
#pragma unroll
      for (int i = 0; i < 16; ++i) acc[m][n][i] = 0;
  v4i af0, af1, af2, af3, bf0, bf1;
  v4i ag0, ag1, ag2, ag3, bg0, bg1;
  int ipv[2][2];

  // prologue: stage tile 0 -> buf0 (8 loads), drain h0, sync
  STAGE_A_(0, 0, 0); STAGE_B_(0, 0, 0); STAGE_A_(0, 1, 0); STAGE_B_(0, 1, 0);
  WAIT_VM4(); BARRIER(); SB();

  // fully unrolled 64 regions (compile-time RIDX for inp pair / acc indices)
  QUAD(0)  QUAD(1)  QUAD(2)  QUAD(3)  QUAD(4)
  QUAD(5)  QUAD(6)  QUAD(7)  QUAD(8)  QUAD(9)
  QUAD(10) QUAD(11) QUAD(12) QUAD(13) QUAD(14)
  REGION(0, 0, 31, 1, WAIT_VM6(), 1, 60);
  REGION(0, 1, 31, 1, WAIT_VM6(), 1, 61);
  // tile 31: no staging; region 62 must drain h1's stages before h1 reads
  REGION(1, 0, 0, 0, WAIT_VM0(), 1, 62);
  REGION(1, 1, 0, 0, NOWAIT(), 0, 63);  // last half, no sync needed after

  // add the last inp pair (compiler inserts its own waitcnt for the loads)
  acc[3][0][15] += ipv[1][0];
  acc[3][1][15] += ipv[1][1];

  // epilogue: stores only. 32x32 C/D layout col=lane&31,
  // row=(reg&3)+8*(reg>>2)+4*khalf. inp was accumulated in-loop.
#pragma unroll
  for (int mb = 0; mb < 4; ++mb) {
#pragma unroll
    for (int nb = 0; nb < 2; ++nb) {
      const int col = n0 + wc * 64 + nb * 32 + rl;
      const int row0 = m0 + wr * 128 + mb * 32 + 4 * khalf;
#pragma unroll
      for (int r = 0; r < 16; ++r) {
        const int row = row0 + (r & 3) + 8 * (r >> 2);
        const size_t idx = (size_t)row * MK + col;
        __builtin_nontemporal_store((float)acc[mb][nb][r], out + idx);
      }
    }
  }
}

// ---------------- fallback (only if ws too small): naive tiled int32 -------
__global__ void fallback_kernel(const int* __restrict__ mat1, const int* __restrict__ mat2,
                                const int* __restrict__ inp, float* __restrict__ out) {
  __shared__ int As[16][16], Bs[16][17];
  int tx = threadIdx.x, ty = threadIdx.y;
  int row = blockIdx.y * 16 + ty, col = blockIdx.x * 16 + tx;
  int acc = 0;
  for (int kt = 0; kt < MK / 16; ++kt) {
    As[ty][tx] = mat1[(size_t)row * MK + kt * 16 + tx];
    Bs[ty][tx] = mat2[(size_t)(kt * 16 + ty) * MK + col];
    __syncthreads();
#pragma unroll
    for (int k = 0; k < 16; ++k) acc += As[ty][k] * Bs[k][tx];
    __syncthreads();
  }
  size_t idx = (size_t)row * MK + col;
  out[idx] = (float)(acc + inp[idx]);
}

extern "C" void kernel_launch(void* const* d_in, const int* in_sizes, int n_in,
                              void* d_out, int out_size, void* d_ws, size_t ws_size,
                              hipStream_t stream) {
  const int* inp = (const int*)d_in[0];
  const int* mat1 = (const int*)d_in[1];
  const int* mat2 = (const int*)d_in[2];
  float* out = (float*)d_out;

  const size_t need = 2 * (size_t)MK * MK;
  if (ws_size >= need) {
    char* A8 = (char*)d_ws;
    char* B8T = A8 + (size_t)MK * MK;
    cvt_kernel<<<6144, 256, 0, stream>>>(mat1, A8, mat2, B8T);
    (void)hipFuncSetAttribute((const void*)gemm_i8_kernel,
                              hipFuncAttributeMaxDynamicSharedMemorySize, 131072);
    gemm_i8_kernel<<<256, 512, 131072, stream>>>(A8, B8T, inp, out);
  } else {
    dim3 blk(16, 16), grd(MK / 16, MK / 16);
    fallback_kernel<<<grd, blk, 0, stream>>>(mat1, mat2, inp, out);
  }
}